// Round 5
// baseline (254.279 us; speedup 1.0000x reference)
//
#include <hip/hip_runtime.h>

using sh8 = __attribute__((ext_vector_type(8))) short;
using sh4 = __attribute__((ext_vector_type(4))) short;
using fx4 = __attribute__((ext_vector_type(4))) float;

#define MFMA(a,b,c)   __builtin_amdgcn_mfma_f32_16x16x32_bf16((a),(b),(c),0,0,0)
#define MFMA16(a,b,c) __builtin_amdgcn_mfma_f32_16x16x16bf16_1k((a),(b),(c),0,0,0)

// RNE cast (epilogue scalars — accuracy-critical path)
__device__ __forceinline__ short f2bf(float f) {
    union { float f; unsigned u; } v; v.f = f;
    return (short)((v.u + 0x7fffu + ((v.u >> 16) & 1u)) >> 16);
}

// Round-half-up pack of two floats to a bf16 pair (3 VALU: 2 add + 1 perm).
__device__ __forceinline__ unsigned bfpair(float lo, float hi) {
    unsigned ul = __float_as_uint(lo) + 0x8000u;
    unsigned uh = __float_as_uint(hi) + 0x8000u;
    return __builtin_amdgcn_perm(uh, ul, 0x07060302);  // [hi.bf16 : lo.bf16]
}

__device__ __forceinline__ sh8 pack8(float4 a, float4 b) {
    union { unsigned u[4]; sh8 s; } r;
    r.u[0] = bfpair(a.x, a.y);
    r.u[1] = bfpair(a.z, a.w);
    r.u[2] = bfpair(b.x, b.y);
    r.u[3] = bfpair(b.z, b.w);
    return r.s;
}

__device__ __forceinline__ sh4 lo4(sh8 v) { return __builtin_shufflevector(v, v, 0, 1, 2, 3); }
__device__ __forceinline__ sh4 hi4(sh8 v) { return __builtin_shufflevector(v, v, 4, 5, 6, 7); }

// q scale: D^-0.5 * log2(e) folded together; attn uses exp2 directly.
#define QSCALE 0.18033688011112042f

// ===========================================================================
// 128x128-tile bf16 GEMM (m97 structure), fp32 sources packed in-flight.
// ===========================================================================

// ---------------------------------------------------------------------------
// q GEMM: q = (x @ Wq^T + bq) * QSCALE -> bf16 q_ws[b][h][qi=n*6+g][d]
// grid (6, 64), 256 thr.
// ---------------------------------------------------------------------------
__global__ __launch_bounds__(256) void qgemm_k(const float* __restrict__ x,
                                               const float* __restrict__ Wq,
                                               const float* __restrict__ bq,
                                               short* __restrict__ q_ws)
{
    __shared__ alignas(16) short Al[128 * 40];
    __shared__ alignas(16) short Bl[128 * 40];
    const int t    = threadIdx.x;
    const int wave = t >> 6, lane = t & 63;
    const int wm   = wave >> 1, wn = wave & 1;
    const int lhi  = lane >> 4, llo = lane & 15;
    const int bm   = blockIdx.y * 128, bn = blockIdx.x * 128;

    const int srow = t >> 1, scol = (t & 1) * 16;
    const float* ap = x  + (size_t)(bm + srow) * 768 + scol;
    const float* bp = Wq + (size_t)(bn + srow) * 768 + scol;

    fx4 zero = {0.f, 0.f, 0.f, 0.f};
    fx4 acc[4][4];
    #pragma unroll
    for (int i = 0; i < 4; ++i)
        #pragma unroll
        for (int j = 0; j < 4; ++j) acc[i][j] = zero;

    float4 pa0 = *(const float4*)(ap);     float4 pa1 = *(const float4*)(ap + 4);
    float4 pa2 = *(const float4*)(ap + 8); float4 pa3 = *(const float4*)(ap + 12);
    float4 pb0 = *(const float4*)(bp);     float4 pb1 = *(const float4*)(bp + 4);
    float4 pb2 = *(const float4*)(bp + 8); float4 pb3 = *(const float4*)(bp + 12);

    for (int k0 = 0; k0 < 768; k0 += 32) {
        __syncthreads();
        *(sh8*)&Al[srow*40 + scol]     = pack8(pa0, pa1);
        *(sh8*)&Al[srow*40 + scol + 8] = pack8(pa2, pa3);
        *(sh8*)&Bl[srow*40 + scol]     = pack8(pb0, pb1);
        *(sh8*)&Bl[srow*40 + scol + 8] = pack8(pb2, pb3);
        __syncthreads();
        if (k0 + 32 < 768) {
            pa0 = *(const float4*)(ap + k0+32);     pa1 = *(const float4*)(ap + k0+36);
            pa2 = *(const float4*)(ap + k0+40);     pa3 = *(const float4*)(ap + k0+44);
            pb0 = *(const float4*)(bp + k0+32);     pb1 = *(const float4*)(bp + k0+36);
            pb2 = *(const float4*)(bp + k0+40);     pb3 = *(const float4*)(bp + k0+44);
        }
        sh8 af[4], bf[4];
        #pragma unroll
        for (int mt = 0; mt < 4; ++mt)
            af[mt] = *(const sh8*)&Al[(wm*64 + mt*16 + llo)*40 + lhi*8];
        #pragma unroll
        for (int nt = 0; nt < 4; ++nt)
            bf[nt] = *(const sh8*)&Bl[(wn*64 + nt*16 + llo)*40 + lhi*8];
        #pragma unroll
        for (int mt = 0; mt < 4; ++mt)
            #pragma unroll
            for (int nt = 0; nt < 4; ++nt)
                acc[mt][nt] = MFMA(af[mt], bf[nt], acc[mt][nt]);
    }

    #pragma unroll
    for (int nt = 0; nt < 4; ++nt) {
        const int c = bn + wn*64 + nt*16 + llo;
        const float bias = bq[c];
        const int g = c >> 7, h = (c >> 6) & 1, d = c & 63;
        #pragma unroll
        for (int mt = 0; mt < 4; ++mt) {
            const int m0 = bm + wm*64 + mt*16 + lhi*4;
            #pragma unroll
            for (int r = 0; r < 4; ++r) {
                const int m = m0 + r;
                const int b = m >> 10, n = m & 1023;
                const float val = (acc[mt][nt][r] + bias) * QSCALE;
                q_ws[((size_t)(b*2 + h)*6144 + n*6 + g)*64 + d] = f2bf(val);
            }
        }
    }
}

// ---------------------------------------------------------------------------
// kv GEMM: kv = x @ Wkv^T + bkv (256 cols: s*128+h*64+d).  grid (2, 64).
// ---------------------------------------------------------------------------
__global__ __launch_bounds__(256) void kvgemm_k(const float* __restrict__ x,
                                                const float* __restrict__ Wkv,
                                                const float* __restrict__ bkv,
                                                float* __restrict__ ok,
                                                float* __restrict__ ov,
                                                short* __restrict__ k_ws,
                                                short* __restrict__ vT_ws)
{
    __shared__ alignas(16) short Al[128 * 40];
    __shared__ alignas(16) short Bl[128 * 40];
    const int t    = threadIdx.x;
    const int wave = t >> 6, lane = t & 63;
    const int wm   = wave >> 1, wn = wave & 1;
    const int lhi  = lane >> 4, llo = lane & 15;
    const int bm   = blockIdx.y * 128, bn = blockIdx.x * 128;

    const int srow = t >> 1, scol = (t & 1) * 16;
    const float* ap = x   + (size_t)(bm + srow) * 768 + scol;
    const float* bp = Wkv + (size_t)(bn + srow) * 768 + scol;

    fx4 zero = {0.f, 0.f, 0.f, 0.f};
    fx4 acc[4][4];
    #pragma unroll
    for (int i = 0; i < 4; ++i)
        #pragma unroll
        for (int j = 0; j < 4; ++j) acc[i][j] = zero;

    float4 pa0 = *(const float4*)(ap);     float4 pa1 = *(const float4*)(ap + 4);
    float4 pa2 = *(const float4*)(ap + 8); float4 pa3 = *(const float4*)(ap + 12);
    float4 pb0 = *(const float4*)(bp);     float4 pb1 = *(const float4*)(bp + 4);
    float4 pb2 = *(const float4*)(bp + 8); float4 pb3 = *(const float4*)(bp + 12);

    for (int k0 = 0; k0 < 768; k0 += 32) {
        __syncthreads();
        *(sh8*)&Al[srow*40 + scol]     = pack8(pa0, pa1);
        *(sh8*)&Al[srow*40 + scol + 8] = pack8(pa2, pa3);
        *(sh8*)&Bl[srow*40 + scol]     = pack8(pb0, pb1);
        *(sh8*)&Bl[srow*40 + scol + 8] = pack8(pb2, pb3);
        __syncthreads();
        if (k0 + 32 < 768) {
            pa0 = *(const float4*)(ap + k0+32);     pa1 = *(const float4*)(ap + k0+36);
            pa2 = *(const float4*)(ap + k0+40);     pa3 = *(const float4*)(ap + k0+44);
            pb0 = *(const float4*)(bp + k0+32);     pb1 = *(const float4*)(bp + k0+36);
            pb2 = *(const float4*)(bp + k0+40);     pb3 = *(const float4*)(bp + k0+44);
        }
        sh8 af[4], bf[4];
        #pragma unroll
        for (int mt = 0; mt < 4; ++mt)
            af[mt] = *(const sh8*)&Al[(wm*64 + mt*16 + llo)*40 + lhi*8];
        #pragma unroll
        for (int nt = 0; nt < 4; ++nt)
            bf[nt] = *(const sh8*)&Bl[(wn*64 + nt*16 + llo)*40 + lhi*8];
        #pragma unroll
        for (int mt = 0; mt < 4; ++mt)
            #pragma unroll
            for (int nt = 0; nt < 4; ++nt)
                acc[mt][nt] = MFMA(af[mt], bf[nt], acc[mt][nt]);
    }

    #pragma unroll
    for (int nt = 0; nt < 4; ++nt) {
        const int c = bn + wn*64 + nt*16 + llo;     // 0..255
        const float bias = bkv[c];
        const int s = c >> 7, h = (c >> 6) & 1, d = c & 63;
        #pragma unroll
        for (int mt = 0; mt < 4; ++mt) {
            const int m0 = bm + wm*64 + mt*16 + lhi*4;
            const int b = m0 >> 10, n0 = m0 & 1023;
            float vals[4];
            #pragma unroll
            for (int r = 0; r < 4; ++r) vals[r] = acc[mt][nt][r] + bias;
            if (s == 0) {
                #pragma unroll
                for (int r = 0; r < 4; ++r) {
                    ok[((size_t)(b*1024 + n0 + r)*2 + h)*64 + d] = vals[r];
                    k_ws[((size_t)(b*2 + h)*2048 + 1024 + n0 + r)*64 + d] = f2bf(vals[r]);
                }
            } else {
                #pragma unroll
                for (int r = 0; r < 4; ++r)
                    ov[((size_t)(b*1024 + n0 + r)*2 + h)*64 + d] = vals[r];
                short4 pk = make_short4(f2bf(vals[0]), f2bf(vals[1]),
                                        f2bf(vals[2]), f2bf(vals[3]));
                *(short4*)&vT_ws[((size_t)((b*2 + h)*64 + d))*2048 + 1024 + n0] = pk;
            }
        }
    }
}

// ---------------------------------------------------------------------------
// depth_k cast (blocks 0..1023) and depth_v transpose-cast (blocks 1024..1279)
// ---------------------------------------------------------------------------
__global__ __launch_bounds__(256) void castdepth_k(const float* __restrict__ dk,
                                                   const float* __restrict__ dv,
                                                   short* __restrict__ k_ws,
                                                   short* __restrict__ vT_ws)
{
    const int t = threadIdx.x;
    if (blockIdx.x < 1024) {
        const size_t idx4 = ((size_t)blockIdx.x * 256 + t) * 4;
        const int b  = (int)(idx4 >> 17);
        const int rm = (int)(idx4 & 131071);
        const int tt = rm >> 7, h = (rm >> 6) & 1, d = rm & 63;
        float4 v = *(const float4*)(dk + idx4);
        short4 pk = make_short4(f2bf(v.x), f2bf(v.y), f2bf(v.z), f2bf(v.w));
        *(short4*)&k_ws[((size_t)(b*2 + h)*2048 + tt)*64 + d] = pk;
    } else {
        __shared__ alignas(16) short tl[64][72];
        const int tile = blockIdx.x - 1024;          // 0..255
        const int bh = tile >> 4, tb = tile & 15;
        const int b = bh >> 1, h = bh & 1, t0 = tb * 64;
        const int tt = t >> 2, d0 = (t & 3) * 16;
        const float* src = dv + ((size_t)(b*1024 + t0 + tt)*2 + h)*64 + d0;
        float4 v0 = *(const float4*)(src);
        float4 v1 = *(const float4*)(src + 4);
        float4 v2 = *(const float4*)(src + 8);
        float4 v3 = *(const float4*)(src + 12);
        *(sh8*)&tl[tt][d0]     = pack8(v0, v1);
        *(sh8*)&tl[tt][d0 + 8] = pack8(v2, v3);
        __syncthreads();
        const int d = t >> 2, ts0 = (t & 3) * 16;
        sh8 o0, o1;
        #pragma unroll
        for (int i = 0; i < 8; ++i) o0[i] = tl[ts0 + i][d];
        #pragma unroll
        for (int i = 0; i < 8; ++i) o1[i] = tl[ts0 + 8 + i][d];
        short* dst = vT_ws + ((size_t)((b*2 + h)*64 + d))*2048 + t0 + ts0;
        *(sh8*)dst       = o0;
        *(sh8*)(dst + 8) = o1;
    }
}

// ---------------------------------------------------------------------------
// Attention v3 (S^T scheme + permuted Vt + global prefetch).
// Vt LDS column map: col(k) = ((k>>2)&3)*16 + (k>>4)*4 + (k&3) — lane
// (llo,lhi)'s V-fragments for ALL 4 nt subtiles sit at cols lhi*16..+15
// (two b128 reads, bank-conflict-free at stride 72).
// grid (48, 16), 256 thr.
// ---------------------------------------------------------------------------
__global__ __launch_bounds__(256) void attn_k(const short* __restrict__ q_ws,
                                              const short* __restrict__ k_ws,
                                              const short* __restrict__ vT_ws,
                                              short* __restrict__ o_ws)
{
    __shared__ alignas(16) short Kl[64][72];   // [key_local][d]
    __shared__ alignas(16) short Vt[64][72];   // [d][permuted key col]
    const int t    = threadIdx.x;
    const int wave = t >> 6, lane = t & 63;
    const int lhi  = lane >> 4, llo = lane & 15;
    const int bh   = blockIdx.y;
    const int b    = bh >> 1, h = bh & 1;
    const int qt   = blockIdx.x;               // 128-q tile index

    const short* qb = q_ws + ((size_t)bh*6144 + qt*128 + wave*32) * 64;
    sh8 qf[2][2];
    #pragma unroll
    for (int s = 0; s < 2; ++s) {
        qf[s][0] = *(const sh8*)(qb + (s*16 + llo)*64 + lhi*8);
        qf[s][1] = *(const sh8*)(qb + (s*16 + llo)*64 + lhi*8 + 32);
    }

    const short* kbase = k_ws  + (size_t)bh * 2048 * 64;
    const short* vbase = vT_ws + (size_t)bh * 64 * 2048;

    // staging coords: thread handles u=t and u=t+256
    const int urow = t >> 3, uc = t & 7;           // K row / 8-short chunk
    const int vc1  = ((uc & 1) * 2) * 16 + (uc >> 1) * 4;   // permuted col, lo half

    const short* kp = kbase + t * 8;
    const short* vp = vbase + (size_t)urow * 2048 + uc * 8;

    sh8 kpre0 = *(const sh8*)(kp);
    sh8 kpre1 = *(const sh8*)(kp + 2048);
    sh8 vpre0 = *(const sh8*)(vp);
    sh8 vpre1 = *(const sh8*)(vp + 65536);

    fx4 zero = {0.f, 0.f, 0.f, 0.f};
    fx4 oacc[2][4];
    #pragma unroll
    for (int s = 0; s < 2; ++s)
        #pragma unroll
        for (int dt = 0; dt < 4; ++dt) oacc[s][dt] = zero;
    float lsum[2] = {0.f, 0.f};

    for (int kb = 0; kb < 32; ++kb) {
        __syncthreads();
        *(sh8*)&Kl[urow][uc*8]         = kpre0;
        *(sh8*)&Kl[urow + 32][uc*8]    = kpre1;
        *(sh4*)&Vt[urow][vc1]          = lo4(vpre0);
        *(sh4*)&Vt[urow][vc1 + 16]     = hi4(vpre0);
        *(sh4*)&Vt[urow + 32][vc1]     = lo4(vpre1);
        *(sh4*)&Vt[urow + 32][vc1 + 16]= hi4(vpre1);
        __syncthreads();

        if (kb < 31) {          // prefetch next key-block while computing
            kpre0 = *(const sh8*)(kp + (kb+1)*4096);
            kpre1 = *(const sh8*)(kp + (kb+1)*4096 + 2048);
            vpre0 = *(const sh8*)(vp + (kb+1)*64);
            vpre1 = *(const sh8*)(vp + (kb+1)*64 + 65536);
        }

        // V fragments for all nt: two b128 per dt, sliced in registers
        sh4 vts[4][4];
        #pragma unroll
        for (int dt = 0; dt < 4; ++dt) {
            sh8 va = *(const sh8*)&Vt[dt*16 + llo][lhi*16];
            sh8 vb = *(const sh8*)&Vt[dt*16 + llo][lhi*16 + 8];
            vts[0][dt] = lo4(va); vts[1][dt] = hi4(va);
            vts[2][dt] = lo4(vb); vts[3][dt] = hi4(vb);
        }

        #pragma unroll
        for (int nt = 0; nt < 4; ++nt) {
            sh8 kf0 = *(const sh8*)&Kl[nt*16 + llo][lhi*8];
            sh8 kf1 = *(const sh8*)&Kl[nt*16 + llo][lhi*8 + 32];
            #pragma unroll
            for (int s = 0; s < 2; ++s) {
                fx4 st = MFMA(kf0, qf[s][0], zero);
                st     = MFMA(kf1, qf[s][1], st);
                float p0 = __builtin_amdgcn_exp2f(st[0]);
                float p1 = __builtin_amdgcn_exp2f(st[1]);
                float p2 = __builtin_amdgcn_exp2f(st[2]);
                float p3 = __builtin_amdgcn_exp2f(st[3]);
                lsum[s] += (p0 + p1) + (p2 + p3);
                union { unsigned u[2]; sh4 s4; } pu;
                pu.u[0] = bfpair(p0, p1);
                pu.u[1] = bfpair(p2, p3);
                #pragma unroll
                for (int dt = 0; dt < 4; ++dt)
                    oacc[s][dt] = MFMA16(pu.s4, vts[nt][dt], oacc[s][dt]);
            }
        }
    }

    float inv[2];
    #pragma unroll
    for (int s = 0; s < 2; ++s) {
        float v = lsum[s];
        v += __shfl_xor(v, 16, 64);
        v += __shfl_xor(v, 32, 64);
        inv[s] = 1.0f / v;
    }

    #pragma unroll
    for (int s = 0; s < 2; ++s) {
        #pragma unroll
        for (int r = 0; r < 4; ++r) {
            const float iq = __shfl(inv[s], lhi*4 + r, 64);
            const int qi = qt*128 + wave*32 + s*16 + lhi*4 + r;
            const int n = qi / 6, g = qi % 6;
            short* orow = o_ws + ((size_t)(b*1024 + n))*768 + g*128 + h*64;
            #pragma unroll
            for (int dt = 0; dt < 4; ++dt)
                orow[dt*16 + llo] = f2bf(oacc[s][dt][r] * iq);
        }
    }
}

// ---------------------------------------------------------------------------
// proj GEMM: out = o(8192x768,bf16) @ Wproj^T + bproj -> fp32.  grid (6, 64).
// ---------------------------------------------------------------------------
__global__ __launch_bounds__(256) void projgemm_k(const short* __restrict__ o_ws,
                                                  const float* __restrict__ Wp,
                                                  const float* __restrict__ bpj,
                                                  float* __restrict__ out)
{
    __shared__ alignas(16) short Al[128 * 40];
    __shared__ alignas(16) short Bl[128 * 40];
    const int t    = threadIdx.x;
    const int wave = t >> 6, lane = t & 63;
    const int wm   = wave >> 1, wn = wave & 1;
    const int lhi  = lane >> 4, llo = lane & 15;
    const int bm   = blockIdx.y * 128, bn = blockIdx.x * 128;

    const int srow = t >> 1, scol = (t & 1) * 16;
    const short* ap = o_ws + (size_t)(bm + srow) * 768 + scol;
    const float* bp = Wp   + (size_t)(bn + srow) * 768 + scol;

    fx4 zero = {0.f, 0.f, 0.f, 0.f};
    fx4 acc[4][4];
    #pragma unroll
    for (int i = 0; i < 4; ++i)
        #pragma unroll
        for (int j = 0; j < 4; ++j) acc[i][j] = zero;

    sh8 qa0 = *(const sh8*)(ap), qa1 = *(const sh8*)(ap + 8);
    float4 pb0 = *(const float4*)(bp);     float4 pb1 = *(const float4*)(bp + 4);
    float4 pb2 = *(const float4*)(bp + 8); float4 pb3 = *(const float4*)(bp + 12);

    for (int k0 = 0; k0 < 768; k0 += 32) {
        __syncthreads();
        *(sh8*)&Al[srow*40 + scol]     = qa0;
        *(sh8*)&Al[srow*40 + scol + 8] = qa1;
        *(sh8*)&Bl[srow*40 + scol]     = pack8(pb0, pb1);
        *(sh8*)&Bl[srow*40 + scol + 8] = pack8(pb2, pb3);
        __syncthreads();
        if (k0 + 32 < 768) {
            qa0 = *(const sh8*)(ap + k0+32);  qa1 = *(const sh8*)(ap + k0+40);
            pb0 = *(const float4*)(bp + k0+32);  pb1 = *(const float4*)(bp + k0+36);
            pb2 = *(const float4*)(bp + k0+40);  pb3 = *(const float4*)(bp + k0+44);
        }
        sh8 af[4], bf[4];
        #pragma unroll
        for (int mt = 0; mt < 4; ++mt)
            af[mt] = *(const sh8*)&Al[(wm*64 + mt*16 + llo)*40 + lhi*8];
        #pragma unroll
        for (int nt = 0; nt < 4; ++nt)
            bf[nt] = *(const sh8*)&Bl[(wn*64 + nt*16 + llo)*40 + lhi*8];
        #pragma unroll
        for (int mt = 0; mt < 4; ++mt)
            #pragma unroll
            for (int nt = 0; nt < 4; ++nt)
                acc[mt][nt] = MFMA(af[mt], bf[nt], acc[mt][nt]);
    }

    #pragma unroll
    for (int nt = 0; nt < 4; ++nt) {
        const int c = bn + wn*64 + nt*16 + llo;
        const float bias = bpj[c];
        #pragma unroll
        for (int mt = 0; mt < 4; ++mt) {
            const int m0 = bm + wm*64 + mt*16 + lhi*4;
            #pragma unroll
            for (int r = 0; r < 4; ++r)
                out[(size_t)(m0 + r)*768 + c] = acc[mt][nt][r] + bias;
        }
    }
}

// ---------------------------------------------------------------------------
extern "C" void kernel_launch(void* const* d_in, const int* in_sizes, int n_in,
                              void* d_out, int out_size, void* d_ws, size_t ws_size,
                              hipStream_t stream)
{
    const float* x   = (const float*)d_in[0];
    const float* dk  = (const float*)d_in[1];
    const float* dv  = (const float*)d_in[2];
    const float* Wq  = (const float*)d_in[3];
    const float* bq  = (const float*)d_in[4];
    const float* Wkv = (const float*)d_in[5];
    const float* bkv = (const float*)d_in[6];
    const float* Wp  = (const float*)d_in[7];
    const float* bpj = (const float*)d_in[8];

    float* out = (float*)d_out;
    float* ok  = out + 6291456;            // k output (8,1024,2,64)
    float* ov  = out + 7340032;            // v output

    char* ws = (char*)d_ws;
    short* q_ws  = (short*)(ws);                    // 12,582,912 B
    short* k_ws  = (short*)(ws + 12582912);         //  4,194,304 B
    short* vT_ws = (short*)(ws + 16777216);         //  4,194,304 B
    short* o_ws  = (short*)(ws + 20971520);         // 12,582,912 B  (32 MiB total)

    qgemm_k    <<<dim3(6, 64), 256, 0, stream>>>(x, Wq, bq, q_ws);
    kvgemm_k   <<<dim3(2, 64), 256, 0, stream>>>(x, Wkv, bkv, ok, ov, k_ws, vT_ws);
    castdepth_k<<<dim3(1280),  256, 0, stream>>>(dk, dv, k_ws, vT_ws);
    attn_k     <<<dim3(48, 16), 256, 0, stream>>>(q_ws, k_ws, vT_ws, o_ws);
    projgemm_k <<<dim3(6, 64), 256, 0, stream>>>(o_ws, Wp, bpj, out);
}

// Round 6
// 229.242 us; speedup vs baseline: 1.1092x; 1.1092x over previous
//
#include <hip/hip_runtime.h>

using sh8 = __attribute__((ext_vector_type(8))) short;
using sh4 = __attribute__((ext_vector_type(4))) short;
using fx4 = __attribute__((ext_vector_type(4))) float;

#define MFMA(a,b,c)   __builtin_amdgcn_mfma_f32_16x16x32_bf16((a),(b),(c),0,0,0)
#define MFMA16(a,b,c) __builtin_amdgcn_mfma_f32_16x16x16bf16_1k((a),(b),(c),0,0,0)

// RNE cast (epilogue scalars — accuracy-critical path)
__device__ __forceinline__ short f2bf(float f) {
    union { float f; unsigned u; } v; v.f = f;
    return (short)((v.u + 0x7fffu + ((v.u >> 16) & 1u)) >> 16);
}

// Round-half-up pack of two floats to a bf16 pair (3 VALU: 2 add + 1 perm).
__device__ __forceinline__ unsigned bfpair(float lo, float hi) {
    unsigned ul = __float_as_uint(lo) + 0x8000u;
    unsigned uh = __float_as_uint(hi) + 0x8000u;
    return __builtin_amdgcn_perm(uh, ul, 0x07060302);  // [hi.bf16 : lo.bf16]
}

__device__ __forceinline__ sh8 pack8(float4 a, float4 b) {
    union { unsigned u[4]; sh8 s; } r;
    r.u[0] = bfpair(a.x, a.y);
    r.u[1] = bfpair(a.z, a.w);
    r.u[2] = bfpair(b.x, b.y);
    r.u[3] = bfpair(b.z, b.w);
    return r.s;
}

__device__ __forceinline__ sh4 lo4(sh8 v) { return __builtin_shufflevector(v, v, 0, 1, 2, 3); }
__device__ __forceinline__ sh4 hi4(sh8 v) { return __builtin_shufflevector(v, v, 4, 5, 6, 7); }

// q scale: D^-0.5 * log2(e) folded together; attn uses exp2 directly.
#define QSCALE 0.18033688011112042f

// ===========================================================================
// prep_k: merged qgemm (blocks 0..383) + kvgemm (384..511) + depth cast/
// transpose (512..1791).  All three are mutually independent; merging them
// fills the machine in one dispatch instead of three serialized launches.
// ===========================================================================
__global__ __launch_bounds__(256) void prep_k(const float* __restrict__ x,
                                              const float* __restrict__ Wq,
                                              const float* __restrict__ bq,
                                              const float* __restrict__ Wkv,
                                              const float* __restrict__ bkv,
                                              const float* __restrict__ dk,
                                              const float* __restrict__ dv,
                                              float* __restrict__ ok,
                                              float* __restrict__ ov,
                                              short* __restrict__ q_ws,
                                              short* __restrict__ k_ws,
                                              short* __restrict__ vT_ws)
{
    __shared__ alignas(16) short Al[128 * 40];
    __shared__ alignas(16) short Bl[128 * 40];
    const int blk = blockIdx.x;
    const int t   = threadIdx.x;

    if (blk < 512) {
        // ----- 128x128-tile bf16 GEMM path (qgemm or kvgemm) -----
        const bool isq = (blk < 384);
        const int  i   = isq ? blk : blk - 384;
        const int  nbx = isq ? 6 : 2;
        const int  bm  = (i / nbx) * 128, bn = (i % nbx) * 128;
        const float* Wmat = isq ? Wq : Wkv;

        const int wave = t >> 6, lane = t & 63;
        const int wm   = wave >> 1, wn = wave & 1;
        const int lhi  = lane >> 4, llo = lane & 15;

        const int srow = t >> 1, scol = (t & 1) * 16;
        const float* ap = x    + (size_t)(bm + srow) * 768 + scol;
        const float* bp = Wmat + (size_t)(bn + srow) * 768 + scol;

        fx4 zero = {0.f, 0.f, 0.f, 0.f};
        fx4 acc[4][4];
        #pragma unroll
        for (int a = 0; a < 4; ++a)
            #pragma unroll
            for (int b2 = 0; b2 < 4; ++b2) acc[a][b2] = zero;

        float4 pa0 = *(const float4*)(ap);     float4 pa1 = *(const float4*)(ap + 4);
        float4 pa2 = *(const float4*)(ap + 8); float4 pa3 = *(const float4*)(ap + 12);
        float4 pb0 = *(const float4*)(bp);     float4 pb1 = *(const float4*)(bp + 4);
        float4 pb2 = *(const float4*)(bp + 8); float4 pb3 = *(const float4*)(bp + 12);

        for (int k0 = 0; k0 < 768; k0 += 32) {
            __syncthreads();
            *(sh8*)&Al[srow*40 + scol]     = pack8(pa0, pa1);
            *(sh8*)&Al[srow*40 + scol + 8] = pack8(pa2, pa3);
            *(sh8*)&Bl[srow*40 + scol]     = pack8(pb0, pb1);
            *(sh8*)&Bl[srow*40 + scol + 8] = pack8(pb2, pb3);
            __syncthreads();
            if (k0 + 32 < 768) {
                pa0 = *(const float4*)(ap + k0+32);  pa1 = *(const float4*)(ap + k0+36);
                pa2 = *(const float4*)(ap + k0+40);  pa3 = *(const float4*)(ap + k0+44);
                pb0 = *(const float4*)(bp + k0+32);  pb1 = *(const float4*)(bp + k0+36);
                pb2 = *(const float4*)(bp + k0+40);  pb3 = *(const float4*)(bp + k0+44);
            }
            sh8 af[4], bf[4];
            #pragma unroll
            for (int mt = 0; mt < 4; ++mt)
                af[mt] = *(const sh8*)&Al[(wm*64 + mt*16 + llo)*40 + lhi*8];
            #pragma unroll
            for (int nt = 0; nt < 4; ++nt)
                bf[nt] = *(const sh8*)&Bl[(wn*64 + nt*16 + llo)*40 + lhi*8];
            #pragma unroll
            for (int mt = 0; mt < 4; ++mt)
                #pragma unroll
                for (int nt = 0; nt < 4; ++nt)
                    acc[mt][nt] = MFMA(af[mt], bf[nt], acc[mt][nt]);
        }

        if (isq) {
            #pragma unroll
            for (int nt = 0; nt < 4; ++nt) {
                const int c = bn + wn*64 + nt*16 + llo;
                const float bias = bq[c];
                const int g = c >> 7, h = (c >> 6) & 1, d = c & 63;
                #pragma unroll
                for (int mt = 0; mt < 4; ++mt) {
                    const int m0 = bm + wm*64 + mt*16 + lhi*4;
                    #pragma unroll
                    for (int r = 0; r < 4; ++r) {
                        const int m = m0 + r;
                        const int b = m >> 10, n = m & 1023;
                        const float val = (acc[mt][nt][r] + bias) * QSCALE;
                        q_ws[((size_t)(b*2 + h)*6144 + n*6 + g)*64 + d] = f2bf(val);
                    }
                }
            }
        } else {
            #pragma unroll
            for (int nt = 0; nt < 4; ++nt) {
                const int c = bn + wn*64 + nt*16 + llo;     // 0..255
                const float bias = bkv[c];
                const int s = c >> 7, h = (c >> 6) & 1, d = c & 63;
                #pragma unroll
                for (int mt = 0; mt < 4; ++mt) {
                    const int m0 = bm + wm*64 + mt*16 + lhi*4;
                    const int b = m0 >> 10, n0 = m0 & 1023;
                    float vals[4];
                    #pragma unroll
                    for (int r = 0; r < 4; ++r) vals[r] = acc[mt][nt][r] + bias;
                    if (s == 0) {
                        #pragma unroll
                        for (int r = 0; r < 4; ++r) {
                            ok[((size_t)(b*1024 + n0 + r)*2 + h)*64 + d] = vals[r];
                            k_ws[((size_t)(b*2 + h)*2048 + 1024 + n0 + r)*64 + d] = f2bf(vals[r]);
                        }
                    } else {
                        #pragma unroll
                        for (int r = 0; r < 4; ++r)
                            ov[((size_t)(b*1024 + n0 + r)*2 + h)*64 + d] = vals[r];
                        short4 pk = make_short4(f2bf(vals[0]), f2bf(vals[1]),
                                                f2bf(vals[2]), f2bf(vals[3]));
                        *(short4*)&vT_ws[((size_t)((b*2 + h)*64 + d))*2048 + 1024 + n0] = pk;
                    }
                }
            }
        }
    } else if (blk < 1536) {
        // ----- depth_k cast: [b][tt][h][d] fp32 -> k_ws[b][h][tt][d] bf16 -----
        const size_t idx4 = ((size_t)(blk - 512) * 256 + t) * 4;
        const int b  = (int)(idx4 >> 17);
        const int rm = (int)(idx4 & 131071);
        const int tt = rm >> 7, h = (rm >> 6) & 1, d = rm & 63;
        float4 v = *(const float4*)(dk + idx4);
        short4 pk = make_short4(f2bf(v.x), f2bf(v.y), f2bf(v.z), f2bf(v.w));
        *(short4*)&k_ws[((size_t)(b*2 + h)*2048 + tt)*64 + d] = pk;
    } else {
        // ----- depth_v transpose-cast -> vT_ws[b][h][d][tt] (LDS transpose) -----
        short (*tl)[72] = (short (*)[72])Al;         // reuse 4.6 KB of Al
        const int tile = blk - 1536;                 // 0..255
        const int bh = tile >> 4, tb = tile & 15;
        const int b = bh >> 1, h = bh & 1, t0 = tb * 64;
        const int tt = t >> 2, d0 = (t & 3) * 16;
        const float* src = dv + ((size_t)(b*1024 + t0 + tt)*2 + h)*64 + d0;
        float4 v0 = *(const float4*)(src);
        float4 v1 = *(const float4*)(src + 4);
        float4 v2 = *(const float4*)(src + 8);
        float4 v3 = *(const float4*)(src + 12);
        *(sh8*)&tl[tt][d0]     = pack8(v0, v1);
        *(sh8*)&tl[tt][d0 + 8] = pack8(v2, v3);
        __syncthreads();
        const int d = t >> 2, ts0 = (t & 3) * 16;
        sh8 o0, o1;
        #pragma unroll
        for (int i = 0; i < 8; ++i) o0[i] = tl[ts0 + i][d];
        #pragma unroll
        for (int i = 0; i < 8; ++i) o1[i] = tl[ts0 + 8 + i][d];
        short* dst = vT_ws + ((size_t)((b*2 + h)*64 + d))*2048 + t0 + ts0;
        *(sh8*)dst       = o0;
        *(sh8*)(dst + 8) = o1;
    }
}

// ---------------------------------------------------------------------------
// Attention v4: S^T scheme + permuted Vt + LDS DOUBLE-BUFFER (1 barrier/iter).
// Global loads for kb+1 issue at iteration top, land in LDS at iteration
// bottom — latency hidden by the compute section; registers transient within
// the iteration (no cross-barrier carry -> occupancy preserved).
// Vt column map: col(k) = ((k>>2)&3)*16 + (k>>4)*4 + (k&3); fragment reads
// are b128 conflict-free at stride 72.  grid (48, 16), 256 thr.
// ---------------------------------------------------------------------------
__global__ __launch_bounds__(256) void attn_k(const short* __restrict__ q_ws,
                                              const short* __restrict__ k_ws,
                                              const short* __restrict__ vT_ws,
                                              short* __restrict__ o_ws)
{
    __shared__ alignas(16) short Kl[2][64][72];   // [buf][key_local][d]
    __shared__ alignas(16) short Vt[2][64][72];   // [buf][d][permuted key col]
    const int t    = threadIdx.x;
    const int wave = t >> 6, lane = t & 63;
    const int lhi  = lane >> 4, llo = lane & 15;
    const int bh   = blockIdx.y;
    const int b    = bh >> 1, h = bh & 1;
    const int qt   = blockIdx.x;               // 128-q tile index

    const short* qb = q_ws + ((size_t)bh*6144 + qt*128 + wave*32) * 64;
    sh8 qf[2][2];
    #pragma unroll
    for (int s = 0; s < 2; ++s) {
        qf[s][0] = *(const sh8*)(qb + (s*16 + llo)*64 + lhi*8);
        qf[s][1] = *(const sh8*)(qb + (s*16 + llo)*64 + lhi*8 + 32);
    }

    const short* kbase = k_ws  + (size_t)bh * 2048 * 64;
    const short* vbase = vT_ws + (size_t)bh * 64 * 2048;

    // staging coords: thread owns rows urow and urow+32
    const int urow = t >> 3, uc = t & 7;
    const int vc1  = ((uc & 1) * 2) * 16 + (uc >> 1) * 4;   // permuted col base

    const short* kp = kbase + t * 8;
    const short* vp = vbase + (size_t)urow * 2048 + uc * 8;

    // preload key-block 0 into buffer 0
    {
        sh8 k0 = *(const sh8*)(kp);
        sh8 k1 = *(const sh8*)(kp + 2048);
        sh8 v0 = *(const sh8*)(vp);
        sh8 v1 = *(const sh8*)(vp + 65536);
        *(sh8*)&Kl[0][urow][uc*8]          = k0;
        *(sh8*)&Kl[0][urow + 32][uc*8]     = k1;
        *(sh4*)&Vt[0][urow][vc1]           = lo4(v0);
        *(sh4*)&Vt[0][urow][vc1 + 16]      = hi4(v0);
        *(sh4*)&Vt[0][urow + 32][vc1]      = lo4(v1);
        *(sh4*)&Vt[0][urow + 32][vc1 + 16] = hi4(v1);
    }
    __syncthreads();

    fx4 zero = {0.f, 0.f, 0.f, 0.f};
    fx4 oacc[2][4];
    #pragma unroll
    for (int s = 0; s < 2; ++s)
        #pragma unroll
        for (int dt = 0; dt < 4; ++dt) oacc[s][dt] = zero;
    float lsum[2] = {0.f, 0.f};

    for (int kb = 0; kb < 32; ++kb) {
        const int cur = kb & 1, nxt = cur ^ 1;

        // issue next key-block's global loads NOW; consumed at loop bottom
        sh8 kn0, kn1, vn0, vn1;
        if (kb < 31) {
            kn0 = *(const sh8*)(kp + (kb+1)*4096);
            kn1 = *(const sh8*)(kp + (kb+1)*4096 + 2048);
            vn0 = *(const sh8*)(vp + (kb+1)*64);
            vn1 = *(const sh8*)(vp + (kb+1)*64 + 65536);
        }

        // V fragments for all nt: two b128 per dt, sliced in registers
        sh4 vts[4][4];
        #pragma unroll
        for (int dt = 0; dt < 4; ++dt) {
            sh8 va = *(const sh8*)&Vt[cur][dt*16 + llo][lhi*16];
            sh8 vb = *(const sh8*)&Vt[cur][dt*16 + llo][lhi*16 + 8];
            vts[0][dt] = lo4(va); vts[1][dt] = hi4(va);
            vts[2][dt] = lo4(vb); vts[3][dt] = hi4(vb);
        }

        #pragma unroll
        for (int nt = 0; nt < 4; ++nt) {
            sh8 kf0 = *(const sh8*)&Kl[cur][nt*16 + llo][lhi*8];
            sh8 kf1 = *(const sh8*)&Kl[cur][nt*16 + llo][lhi*8 + 32];
            #pragma unroll
            for (int s = 0; s < 2; ++s) {
                fx4 st = MFMA(kf0, qf[s][0], zero);
                st     = MFMA(kf1, qf[s][1], st);
                float p0 = __builtin_amdgcn_exp2f(st[0]);
                float p1 = __builtin_amdgcn_exp2f(st[1]);
                float p2 = __builtin_amdgcn_exp2f(st[2]);
                float p3 = __builtin_amdgcn_exp2f(st[3]);
                lsum[s] += (p0 + p1) + (p2 + p3);
                union { unsigned u[2]; sh4 s4; } pu;
                pu.u[0] = bfpair(p0, p1);
                pu.u[1] = bfpair(p2, p3);
                #pragma unroll
                for (int dt = 0; dt < 4; ++dt)
                    oacc[s][dt] = MFMA16(pu.s4, vts[nt][dt], oacc[s][dt]);
            }
        }

        // land the prefetched block in the other buffer
        if (kb < 31) {
            *(sh8*)&Kl[nxt][urow][uc*8]          = kn0;
            *(sh8*)&Kl[nxt][urow + 32][uc*8]     = kn1;
            *(sh4*)&Vt[nxt][urow][vc1]           = lo4(vn0);
            *(sh4*)&Vt[nxt][urow][vc1 + 16]      = hi4(vn0);
            *(sh4*)&Vt[nxt][urow + 32][vc1]      = lo4(vn1);
            *(sh4*)&Vt[nxt][urow + 32][vc1 + 16] = hi4(vn1);
        }
        __syncthreads();
    }

    float inv[2];
    #pragma unroll
    for (int s = 0; s < 2; ++s) {
        float v = lsum[s];
        v += __shfl_xor(v, 16, 64);
        v += __shfl_xor(v, 32, 64);
        inv[s] = 1.0f / v;
    }

    #pragma unroll
    for (int s = 0; s < 2; ++s) {
        #pragma unroll
        for (int r = 0; r < 4; ++r) {
            const float iq = __shfl(inv[s], lhi*4 + r, 64);
            const int qi = qt*128 + wave*32 + s*16 + lhi*4 + r;
            const int n = qi / 6, g = qi % 6;
            short* orow = o_ws + ((size_t)(b*1024 + n))*768 + g*128 + h*64;
            #pragma unroll
            for (int dt = 0; dt < 4; ++dt)
                orow[dt*16 + llo] = f2bf(oacc[s][dt][r] * iq);
        }
    }
}

// ---------------------------------------------------------------------------
// proj GEMM: out = o(8192x768,bf16) @ Wproj^T + bproj -> fp32.  grid (6, 64).
// ---------------------------------------------------------------------------
__global__ __launch_bounds__(256) void projgemm_k(const short* __restrict__ o_ws,
                                                  const float* __restrict__ Wp,
                                                  const float* __restrict__ bpj,
                                                  float* __restrict__ out)
{
    __shared__ alignas(16) short Al[128 * 40];
    __shared__ alignas(16) short Bl[128 * 40];
    const int t    = threadIdx.x;
    const int wave = t >> 6, lane = t & 63;
    const int wm   = wave >> 1, wn = wave & 1;
    const int lhi  = lane >> 4, llo = lane & 15;
    const int bm   = blockIdx.y * 128, bn = blockIdx.x * 128;

    const int srow = t >> 1, scol = (t & 1) * 16;
    const short* ap = o_ws + (size_t)(bm + srow) * 768 + scol;
    const float* bp = Wp   + (size_t)(bn + srow) * 768 + scol;

    fx4 zero = {0.f, 0.f, 0.f, 0.f};
    fx4 acc[4][4];
    #pragma unroll
    for (int i = 0; i < 4; ++i)
        #pragma unroll
        for (int j = 0; j < 4; ++j) acc[i][j] = zero;

    sh8 qa0 = *(const sh8*)(ap), qa1 = *(const sh8*)(ap + 8);
    float4 pb0 = *(const float4*)(bp);     float4 pb1 = *(const float4*)(bp + 4);
    float4 pb2 = *(const float4*)(bp + 8); float4 pb3 = *(const float4*)(bp + 12);

    for (int k0 = 0; k0 < 768; k0 += 32) {
        __syncthreads();
        *(sh8*)&Al[srow*40 + scol]     = qa0;
        *(sh8*)&Al[srow*40 + scol + 8] = qa1;
        *(sh8*)&Bl[srow*40 + scol]     = pack8(pb0, pb1);
        *(sh8*)&Bl[srow*40 + scol + 8] = pack8(pb2, pb3);
        __syncthreads();
        if (k0 + 32 < 768) {
            qa0 = *(const sh8*)(ap + k0+32);  qa1 = *(const sh8*)(ap + k0+40);
            pb0 = *(const float4*)(bp + k0+32);  pb1 = *(const float4*)(bp + k0+36);
            pb2 = *(const float4*)(bp + k0+40);  pb3 = *(const float4*)(bp + k0+44);
        }
        sh8 af[4], bf[4];
        #pragma unroll
        for (int mt = 0; mt < 4; ++mt)
            af[mt] = *(const sh8*)&Al[(wm*64 + mt*16 + llo)*40 + lhi*8];
        #pragma unroll
        for (int nt = 0; nt < 4; ++nt)
            bf[nt] = *(const sh8*)&Bl[(wn*64 + nt*16 + llo)*40 + lhi*8];
        #pragma unroll
        for (int mt = 0; mt < 4; ++mt)
            #pragma unroll
            for (int nt = 0; nt < 4; ++nt)
                acc[mt][nt] = MFMA(af[mt], bf[nt], acc[mt][nt]);
    }

    #pragma unroll
    for (int nt = 0; nt < 4; ++nt) {
        const int c = bn + wn*64 + nt*16 + llo;
        const float bias = bpj[c];
        #pragma unroll
        for (int mt = 0; mt < 4; ++mt) {
            const int m0 = bm + wm*64 + mt*16 + lhi*4;
            #pragma unroll
            for (int r = 0; r < 4; ++r)
                out[(size_t)(m0 + r)*768 + c] = acc[mt][nt][r] + bias;
        }
    }
}

// ---------------------------------------------------------------------------
extern "C" void kernel_launch(void* const* d_in, const int* in_sizes, int n_in,
                              void* d_out, int out_size, void* d_ws, size_t ws_size,
                              hipStream_t stream)
{
    const float* x   = (const float*)d_in[0];
    const float* dk  = (const float*)d_in[1];
    const float* dv  = (const float*)d_in[2];
    const float* Wq  = (const float*)d_in[3];
    const float* bq  = (const float*)d_in[4];
    const float* Wkv = (const float*)d_in[5];
    const float* bkv = (const float*)d_in[6];
    const float* Wp  = (const float*)d_in[7];
    const float* bpj = (const float*)d_in[8];

    float* out = (float*)d_out;
    float* ok  = out + 6291456;            // k output (8,1024,2,64)
    float* ov  = out + 7340032;            // v output

    char* ws = (char*)d_ws;
    short* q_ws  = (short*)(ws);                    // 12,582,912 B
    short* k_ws  = (short*)(ws + 12582912);         //  4,194,304 B
    short* vT_ws = (short*)(ws + 16777216);         //  4,194,304 B
    short* o_ws  = (short*)(ws + 20971520);         // 12,582,912 B  (32 MiB total)

    prep_k     <<<dim3(1792),   256, 0, stream>>>(x, Wq, bq, Wkv, bkv, dk, dv,
                                                  ok, ov, q_ws, k_ws, vT_ws);
    attn_k     <<<dim3(48, 16), 256, 0, stream>>>(q_ws, k_ws, vT_ws, o_ws);
    projgemm_k <<<dim3(6, 64),  256, 0, stream>>>(o_ws, Wp, bpj, out);
}

// Round 7
// 222.658 us; speedup vs baseline: 1.1420x; 1.0296x over previous
//
#include <hip/hip_runtime.h>

using sh8 = __attribute__((ext_vector_type(8))) short;
using sh4 = __attribute__((ext_vector_type(4))) short;
using fx4 = __attribute__((ext_vector_type(4))) float;

#define MFMA(a,b,c)   __builtin_amdgcn_mfma_f32_16x16x32_bf16((a),(b),(c),0,0,0)
#define MFMA16(a,b,c) __builtin_amdgcn_mfma_f32_16x16x16bf16_1k((a),(b),(c),0,0,0)

// RNE cast (epilogue scalars — accuracy-critical path)
__device__ __forceinline__ short f2bf(float f) {
    union { float f; unsigned u; } v; v.f = f;
    return (short)((v.u + 0x7fffu + ((v.u >> 16) & 1u)) >> 16);
}

// Round-half-up pack of two floats to a bf16 pair (3 VALU: 2 add + 1 perm).
__device__ __forceinline__ unsigned bfpair(float lo, float hi) {
    unsigned ul = __float_as_uint(lo) + 0x8000u;
    unsigned uh = __float_as_uint(hi) + 0x8000u;
    return __builtin_amdgcn_perm(uh, ul, 0x07060302);  // [hi.bf16 : lo.bf16]
}

__device__ __forceinline__ sh8 pack8(float4 a, float4 b) {
    union { unsigned u[4]; sh8 s; } r;
    r.u[0] = bfpair(a.x, a.y);
    r.u[1] = bfpair(a.z, a.w);
    r.u[2] = bfpair(b.x, b.y);
    r.u[3] = bfpair(b.z, b.w);
    return r.s;
}

__device__ __forceinline__ sh4 lo4(sh8 v) { return __builtin_shufflevector(v, v, 0, 1, 2, 3); }
__device__ __forceinline__ sh4 hi4(sh8 v) { return __builtin_shufflevector(v, v, 4, 5, 6, 7); }

// q scale: D^-0.5 * log2(e) folded together; attn uses exp2 directly.
#define QSCALE 0.18033688011112042f

// ===========================================================================
// prep_k: merged qgemm (blocks 0..383) + kvgemm (384..511) + depth cast/
// transpose (512..1791).
// ===========================================================================
__global__ __launch_bounds__(256) void prep_k(const float* __restrict__ x,
                                              const float* __restrict__ Wq,
                                              const float* __restrict__ bq,
                                              const float* __restrict__ Wkv,
                                              const float* __restrict__ bkv,
                                              const float* __restrict__ dk,
                                              const float* __restrict__ dv,
                                              float* __restrict__ ok,
                                              float* __restrict__ ov,
                                              short* __restrict__ q_ws,
                                              short* __restrict__ k_ws,
                                              short* __restrict__ vT_ws)
{
    __shared__ alignas(16) short Al[128 * 40];
    __shared__ alignas(16) short Bl[128 * 40];
    const int blk = blockIdx.x;
    const int t   = threadIdx.x;

    if (blk < 512) {
        // ----- 128x128-tile bf16 GEMM path (qgemm or kvgemm) -----
        const bool isq = (blk < 384);
        const int  i   = isq ? blk : blk - 384;
        const int  nbx = isq ? 6 : 2;
        const int  bm  = (i / nbx) * 128, bn = (i % nbx) * 128;
        const float* Wmat = isq ? Wq : Wkv;

        const int wave = t >> 6, lane = t & 63;
        const int wm   = wave >> 1, wn = wave & 1;
        const int lhi  = lane >> 4, llo = lane & 15;

        const int srow = t >> 1, scol = (t & 1) * 16;
        const float* ap = x    + (size_t)(bm + srow) * 768 + scol;
        const float* bp = Wmat + (size_t)(bn + srow) * 768 + scol;

        fx4 zero = {0.f, 0.f, 0.f, 0.f};
        fx4 acc[4][4];
        #pragma unroll
        for (int a = 0; a < 4; ++a)
            #pragma unroll
            for (int b2 = 0; b2 < 4; ++b2) acc[a][b2] = zero;

        float4 pa0 = *(const float4*)(ap);     float4 pa1 = *(const float4*)(ap + 4);
        float4 pa2 = *(const float4*)(ap + 8); float4 pa3 = *(const float4*)(ap + 12);
        float4 pb0 = *(const float4*)(bp);     float4 pb1 = *(const float4*)(bp + 4);
        float4 pb2 = *(const float4*)(bp + 8); float4 pb3 = *(const float4*)(bp + 12);

        for (int k0 = 0; k0 < 768; k0 += 32) {
            __syncthreads();
            *(sh8*)&Al[srow*40 + scol]     = pack8(pa0, pa1);
            *(sh8*)&Al[srow*40 + scol + 8] = pack8(pa2, pa3);
            *(sh8*)&Bl[srow*40 + scol]     = pack8(pb0, pb1);
            *(sh8*)&Bl[srow*40 + scol + 8] = pack8(pb2, pb3);
            __syncthreads();
            if (k0 + 32 < 768) {
                pa0 = *(const float4*)(ap + k0+32);  pa1 = *(const float4*)(ap + k0+36);
                pa2 = *(const float4*)(ap + k0+40);  pa3 = *(const float4*)(ap + k0+44);
                pb0 = *(const float4*)(bp + k0+32);  pb1 = *(const float4*)(bp + k0+36);
                pb2 = *(const float4*)(bp + k0+40);  pb3 = *(const float4*)(bp + k0+44);
            }
            sh8 af[4], bf[4];
            #pragma unroll
            for (int mt = 0; mt < 4; ++mt)
                af[mt] = *(const sh8*)&Al[(wm*64 + mt*16 + llo)*40 + lhi*8];
            #pragma unroll
            for (int nt = 0; nt < 4; ++nt)
                bf[nt] = *(const sh8*)&Bl[(wn*64 + nt*16 + llo)*40 + lhi*8];
            #pragma unroll
            for (int mt = 0; mt < 4; ++mt)
                #pragma unroll
                for (int nt = 0; nt < 4; ++nt)
                    acc[mt][nt] = MFMA(af[mt], bf[nt], acc[mt][nt]);
        }

        if (isq) {
            #pragma unroll
            for (int nt = 0; nt < 4; ++nt) {
                const int c = bn + wn*64 + nt*16 + llo;
                const float bias = bq[c];
                const int g = c >> 7, h = (c >> 6) & 1, d = c & 63;
                #pragma unroll
                for (int mt = 0; mt < 4; ++mt) {
                    const int m0 = bm + wm*64 + mt*16 + lhi*4;
                    #pragma unroll
                    for (int r = 0; r < 4; ++r) {
                        const int m = m0 + r;
                        const int b = m >> 10, n = m & 1023;
                        const float val = (acc[mt][nt][r] + bias) * QSCALE;
                        q_ws[((size_t)(b*2 + h)*6144 + n*6 + g)*64 + d] = f2bf(val);
                    }
                }
            }
        } else {
            #pragma unroll
            for (int nt = 0; nt < 4; ++nt) {
                const int c = bn + wn*64 + nt*16 + llo;     // 0..255
                const float bias = bkv[c];
                const int s = c >> 7, h = (c >> 6) & 1, d = c & 63;
                #pragma unroll
                for (int mt = 0; mt < 4; ++mt) {
                    const int m0 = bm + wm*64 + mt*16 + lhi*4;
                    const int b = m0 >> 10, n0 = m0 & 1023;
                    float vals[4];
                    #pragma unroll
                    for (int r = 0; r < 4; ++r) vals[r] = acc[mt][nt][r] + bias;
                    if (s == 0) {
                        #pragma unroll
                        for (int r = 0; r < 4; ++r) {
                            ok[((size_t)(b*1024 + n0 + r)*2 + h)*64 + d] = vals[r];
                            k_ws[((size_t)(b*2 + h)*2048 + 1024 + n0 + r)*64 + d] = f2bf(vals[r]);
                        }
                    } else {
                        #pragma unroll
                        for (int r = 0; r < 4; ++r)
                            ov[((size_t)(b*1024 + n0 + r)*2 + h)*64 + d] = vals[r];
                        short4 pk = make_short4(f2bf(vals[0]), f2bf(vals[1]),
                                                f2bf(vals[2]), f2bf(vals[3]));
                        *(short4*)&vT_ws[((size_t)((b*2 + h)*64 + d))*2048 + 1024 + n0] = pk;
                    }
                }
            }
        }
    } else if (blk < 1536) {
        // ----- depth_k cast: [b][tt][h][d] fp32 -> k_ws[b][h][tt][d] bf16 -----
        const size_t idx4 = ((size_t)(blk - 512) * 256 + t) * 4;
        const int b  = (int)(idx4 >> 17);
        const int rm = (int)(idx4 & 131071);
        const int tt = rm >> 7, h = (rm >> 6) & 1, d = rm & 63;
        float4 v = *(const float4*)(dk + idx4);
        short4 pk = make_short4(f2bf(v.x), f2bf(v.y), f2bf(v.z), f2bf(v.w));
        *(short4*)&k_ws[((size_t)(b*2 + h)*2048 + tt)*64 + d] = pk;
    } else {
        // ----- depth_v transpose-cast -> vT_ws[b][h][d][tt] (LDS transpose) -----
        short (*tl)[72] = (short (*)[72])Al;         // reuse 4.6 KB of Al
        const int tile = blk - 1536;                 // 0..255
        const int bh = tile >> 4, tb = tile & 15;
        const int b = bh >> 1, h = bh & 1, t0 = tb * 64;
        const int tt = t >> 2, d0 = (t & 3) * 16;
        const float* src = dv + ((size_t)(b*1024 + t0 + tt)*2 + h)*64 + d0;
        float4 v0 = *(const float4*)(src);
        float4 v1 = *(const float4*)(src + 4);
        float4 v2 = *(const float4*)(src + 8);
        float4 v3 = *(const float4*)(src + 12);
        *(sh8*)&tl[tt][d0]     = pack8(v0, v1);
        *(sh8*)&tl[tt][d0 + 8] = pack8(v2, v3);
        __syncthreads();
        const int d = t >> 2, ts0 = (t & 3) * 16;
        sh8 o0, o1;
        #pragma unroll
        for (int i = 0; i < 8; ++i) o0[i] = tl[ts0 + i][d];
        #pragma unroll
        for (int i = 0; i < 8; ++i) o1[i] = tl[ts0 + 8 + i][d];
        short* dst = vT_ws + ((size_t)((b*2 + h)*64 + d))*2048 + t0 + ts0;
        *(sh8*)dst       = o0;
        *(sh8*)(dst + 8) = o1;
    }
}

// ---------------------------------------------------------------------------
// Attention v5: 192 q/block (48 q/wave as 3 subtiles) — K/V LDS reads per
// keyblock are q-invariant, so 1.5x q/wave cuts LDS read traffic per unit
// work by 1/3.  Grid 32x16 = 512 blocks = exactly 2/CU (balanced).
// Keeps: S^T scheme, permuted Vt (b128 conflict-free frag reads), LDS
// double-buffer with 1 barrier/iter, exp2, bfpair pack.
// ---------------------------------------------------------------------------
__global__ __launch_bounds__(256) void attn_k(const short* __restrict__ q_ws,
                                              const short* __restrict__ k_ws,
                                              const short* __restrict__ vT_ws,
                                              short* __restrict__ o_ws)
{
    __shared__ alignas(16) short Kl[2][64][72];   // [buf][key_local][d]
    __shared__ alignas(16) short Vt[2][64][72];   // [buf][d][permuted key col]
    const int t    = threadIdx.x;
    const int wave = t >> 6, lane = t & 63;
    const int lhi  = lane >> 4, llo = lane & 15;
    const int bh   = blockIdx.y;
    const int b    = bh >> 1, h = bh & 1;
    const int qt   = blockIdx.x;               // 192-q tile index

    const short* qb = q_ws + ((size_t)bh*6144 + qt*192 + wave*48) * 64;
    sh8 qf[3][2];
    #pragma unroll
    for (int s = 0; s < 3; ++s) {
        qf[s][0] = *(const sh8*)(qb + (s*16 + llo)*64 + lhi*8);
        qf[s][1] = *(const sh8*)(qb + (s*16 + llo)*64 + lhi*8 + 32);
    }

    const short* kbase = k_ws  + (size_t)bh * 2048 * 64;
    const short* vbase = vT_ws + (size_t)bh * 64 * 2048;

    // staging coords: thread owns rows urow and urow+32
    const int urow = t >> 3, uc = t & 7;
    const int vc1  = ((uc & 1) * 2) * 16 + (uc >> 1) * 4;   // permuted col base

    const short* kp = kbase + t * 8;
    const short* vp = vbase + (size_t)urow * 2048 + uc * 8;

    // preload key-block 0 into buffer 0
    {
        sh8 k0 = *(const sh8*)(kp);
        sh8 k1 = *(const sh8*)(kp + 2048);
        sh8 v0 = *(const sh8*)(vp);
        sh8 v1 = *(const sh8*)(vp + 65536);
        *(sh8*)&Kl[0][urow][uc*8]          = k0;
        *(sh8*)&Kl[0][urow + 32][uc*8]     = k1;
        *(sh4*)&Vt[0][urow][vc1]           = lo4(v0);
        *(sh4*)&Vt[0][urow][vc1 + 16]      = hi4(v0);
        *(sh4*)&Vt[0][urow + 32][vc1]      = lo4(v1);
        *(sh4*)&Vt[0][urow + 32][vc1 + 16] = hi4(v1);
    }
    __syncthreads();

    fx4 zero = {0.f, 0.f, 0.f, 0.f};
    fx4 oacc[3][4];
    #pragma unroll
    for (int s = 0; s < 3; ++s)
        #pragma unroll
        for (int dt = 0; dt < 4; ++dt) oacc[s][dt] = zero;
    float lsum[3] = {0.f, 0.f, 0.f};

    for (int kb = 0; kb < 32; ++kb) {
        const int cur = kb & 1, nxt = cur ^ 1;

        // issue next key-block's global loads NOW; consumed at loop bottom
        sh8 kn0, kn1, vn0, vn1;
        if (kb < 31) {
            kn0 = *(const sh8*)(kp + (kb+1)*4096);
            kn1 = *(const sh8*)(kp + (kb+1)*4096 + 2048);
            vn0 = *(const sh8*)(vp + (kb+1)*64);
            vn1 = *(const sh8*)(vp + (kb+1)*64 + 65536);
        }

        // V fragments for all nt: two b128 per dt, sliced in registers
        sh4 vts[4][4];
        #pragma unroll
        for (int dt = 0; dt < 4; ++dt) {
            sh8 va = *(const sh8*)&Vt[cur][dt*16 + llo][lhi*16];
            sh8 vb = *(const sh8*)&Vt[cur][dt*16 + llo][lhi*16 + 8];
            vts[0][dt] = lo4(va); vts[1][dt] = hi4(va);
            vts[2][dt] = lo4(vb); vts[3][dt] = hi4(vb);
        }

        #pragma unroll
        for (int nt = 0; nt < 4; ++nt) {
            sh8 kf0 = *(const sh8*)&Kl[cur][nt*16 + llo][lhi*8];
            sh8 kf1 = *(const sh8*)&Kl[cur][nt*16 + llo][lhi*8 + 32];
            #pragma unroll
            for (int s = 0; s < 3; ++s) {
                fx4 st = MFMA(kf0, qf[s][0], zero);
                st     = MFMA(kf1, qf[s][1], st);
                float p0 = __builtin_amdgcn_exp2f(st[0]);
                float p1 = __builtin_amdgcn_exp2f(st[1]);
                float p2 = __builtin_amdgcn_exp2f(st[2]);
                float p3 = __builtin_amdgcn_exp2f(st[3]);
                lsum[s] += (p0 + p1) + (p2 + p3);
                union { unsigned u[2]; sh4 s4; } pu;
                pu.u[0] = bfpair(p0, p1);
                pu.u[1] = bfpair(p2, p3);
                #pragma unroll
                for (int dt = 0; dt < 4; ++dt)
                    oacc[s][dt] = MFMA16(pu.s4, vts[nt][dt], oacc[s][dt]);
            }
        }

        // land the prefetched block in the other buffer
        if (kb < 31) {
            *(sh8*)&Kl[nxt][urow][uc*8]          = kn0;
            *(sh8*)&Kl[nxt][urow + 32][uc*8]     = kn1;
            *(sh4*)&Vt[nxt][urow][vc1]           = lo4(vn0);
            *(sh4*)&Vt[nxt][urow][vc1 + 16]      = hi4(vn0);
            *(sh4*)&Vt[nxt][urow + 32][vc1]      = lo4(vn1);
            *(sh4*)&Vt[nxt][urow + 32][vc1 + 16] = hi4(vn1);
        }
        __syncthreads();
    }

    float inv[3];
    #pragma unroll
    for (int s = 0; s < 3; ++s) {
        float v = lsum[s];
        v += __shfl_xor(v, 16, 64);
        v += __shfl_xor(v, 32, 64);
        inv[s] = 1.0f / v;
    }

    #pragma unroll
    for (int s = 0; s < 3; ++s) {
        #pragma unroll
        for (int r = 0; r < 4; ++r) {
            const float iq = __shfl(inv[s], lhi*4 + r, 64);
            const int qi = qt*192 + wave*48 + s*16 + lhi*4 + r;
            const int n = qi / 6, g = qi % 6;
            short* orow = o_ws + ((size_t)(b*1024 + n))*768 + g*128 + h*64;
            #pragma unroll
            for (int dt = 0; dt < 4; ++dt)
                orow[dt*16 + llo] = f2bf(oacc[s][dt][r] * iq);
        }
    }
}

// ---------------------------------------------------------------------------
// proj GEMM: out = o(8192x768,bf16) @ Wproj^T + bproj -> fp32.  grid (6, 64).
// ---------------------------------------------------------------------------
__global__ __launch_bounds__(256) void projgemm_k(const short* __restrict__ o_ws,
                                                  const float* __restrict__ Wp,
                                                  const float* __restrict__ bpj,
                                                  float* __restrict__ out)
{
    __shared__ alignas(16) short Al[128 * 40];
    __shared__ alignas(16) short Bl[128 * 40];
    const int t    = threadIdx.x;
    const int wave = t >> 6, lane = t & 63;
    const int wm   = wave >> 1, wn = wave & 1;
    const int lhi  = lane >> 4, llo = lane & 15;
    const int bm   = blockIdx.y * 128, bn = blockIdx.x * 128;

    const int srow = t >> 1, scol = (t & 1) * 16;
    const short* ap = o_ws + (size_t)(bm + srow) * 768 + scol;
    const float* bp = Wp   + (size_t)(bn + srow) * 768 + scol;

    fx4 zero = {0.f, 0.f, 0.f, 0.f};
    fx4 acc[4][4];
    #pragma unroll
    for (int i = 0; i < 4; ++i)
        #pragma unroll
        for (int j = 0; j < 4; ++j) acc[i][j] = zero;

    sh8 qa0 = *(const sh8*)(ap), qa1 = *(const sh8*)(ap + 8);
    float4 pb0 = *(const float4*)(bp);     float4 pb1 = *(const float4*)(bp + 4);
    float4 pb2 = *(const float4*)(bp + 8); float4 pb3 = *(const float4*)(bp + 12);

    for (int k0 = 0; k0 < 768; k0 += 32) {
        __syncthreads();
        *(sh8*)&Al[srow*40 + scol]     = qa0;
        *(sh8*)&Al[srow*40 + scol + 8] = qa1;
        *(sh8*)&Bl[srow*40 + scol]     = pack8(pb0, pb1);
        *(sh8*)&Bl[srow*40 + scol + 8] = pack8(pb2, pb3);
        __syncthreads();
        if (k0 + 32 < 768) {
            qa0 = *(const sh8*)(ap + k0+32);  qa1 = *(const sh8*)(ap + k0+40);
            pb0 = *(const float4*)(bp + k0+32);  pb1 = *(const float4*)(bp + k0+36);
            pb2 = *(const float4*)(bp + k0+40);  pb3 = *(const float4*)(bp + k0+44);
        }
        sh8 af[4], bf[4];
        #pragma unroll
        for (int mt = 0; mt < 4; ++mt)
            af[mt] = *(const sh8*)&Al[(wm*64 + mt*16 + llo)*40 + lhi*8];
        #pragma unroll
        for (int nt = 0; nt < 4; ++nt)
            bf[nt] = *(const sh8*)&Bl[(wn*64 + nt*16 + llo)*40 + lhi*8];
        #pragma unroll
        for (int mt = 0; mt < 4; ++mt)
            #pragma unroll
            for (int nt = 0; nt < 4; ++nt)
                acc[mt][nt] = MFMA(af[mt], bf[nt], acc[mt][nt]);
    }

    #pragma unroll
    for (int nt = 0; nt < 4; ++nt) {
        const int c = bn + wn*64 + nt*16 + llo;
        const float bias = bpj[c];
        #pragma unroll
        for (int mt = 0; mt < 4; ++mt) {
            const int m0 = bm + wm*64 + mt*16 + lhi*4;
            #pragma unroll
            for (int r = 0; r < 4; ++r)
                out[(size_t)(m0 + r)*768 + c] = acc[mt][nt][r] + bias;
        }
    }
}

// ---------------------------------------------------------------------------
extern "C" void kernel_launch(void* const* d_in, const int* in_sizes, int n_in,
                              void* d_out, int out_size, void* d_ws, size_t ws_size,
                              hipStream_t stream)
{
    const float* x   = (const float*)d_in[0];
    const float* dk  = (const float*)d_in[1];
    const float* dv  = (const float*)d_in[2];
    const float* Wq  = (const float*)d_in[3];
    const float* bq  = (const float*)d_in[4];
    const float* Wkv = (const float*)d_in[5];
    const float* bkv = (const float*)d_in[6];
    const float* Wp  = (const float*)d_in[7];
    const float* bpj = (const float*)d_in[8];

    float* out = (float*)d_out;
    float* ok  = out + 6291456;            // k output (8,1024,2,64)
    float* ov  = out + 7340032;            // v output

    char* ws = (char*)d_ws;
    short* q_ws  = (short*)(ws);                    // 12,582,912 B
    short* k_ws  = (short*)(ws + 12582912);         //  4,194,304 B
    short* vT_ws = (short*)(ws + 16777216);         //  4,194,304 B
    short* o_ws  = (short*)(ws + 20971520);         // 12,582,912 B  (32 MiB total)

    prep_k     <<<dim3(1792),   256, 0, stream>>>(x, Wq, bq, Wkv, bkv, dk, dv,
                                                  ok, ov, q_ws, k_ws, vT_ws);
    attn_k     <<<dim3(32, 16), 256, 0, stream>>>(q_ws, k_ws, vT_ws, o_ws);
    projgemm_k <<<dim3(6, 64),  256, 0, stream>>>(o_ws, Wp, bpj, out);
}